// Round 7
// baseline (629.792 us; speedup 1.0000x reference)
//
#include <hip/hip_runtime.h>
#include <math.h>

#define B_ROWS 32768
#define N_SLOTS 2048
#define H_DIM 512
#define MCAP 4096

typedef __attribute__((ext_vector_type(8))) _Float16 f16x8;
typedef __attribute__((ext_vector_type(4))) float f32x4;

#define ZPL 132   // Pl stride (shorts)
#define FIX_MARGIN 2.5e-4f   // fp16 sims: gap-error sigma ~5e-5 -> 4.6 sigma margin
#define XROWS 16

__device__ __forceinline__ unsigned short f2h(float f) {
    union { _Float16 h; unsigned short u; } cv;
    cv.h = (_Float16)f;          // v_cvt_f16_f32, RTN
    return cv.u;
}
__device__ __forceinline__ unsigned pk2h(float a, float b) {
    return (unsigned)f2h(a) | ((unsigned)f2h(b) << 16);
}
// monotonic float->uint encode: a > b  <=>  fenc(a) > fenc(b)
__device__ __forceinline__ unsigned fenc(float f) {
    unsigned b = __float_as_uint(f);
    return (b & 0x80000000u) ? ~b : (b | 0x80000000u);
}

// async global->LDS, 16B per lane, LDS dest = wave-uniform base + lane*16
#define STAGE16(g, l) __builtin_amdgcn_global_load_lds( \
    (const __attribute__((address_space(1))) unsigned int*)(g), \
    (__attribute__((address_space(3))) unsigned int*)(l), 16, 0, 0)

// counted waits + raw barrier (T4): keep prefetch in flight across barriers
#define VWAIT4() asm volatile("s_waitcnt vmcnt(4)" ::: "memory")
#define LWAIT0() asm volatile("s_waitcnt lgkmcnt(0)" ::: "memory")

// ---------------- prep: reciprocal norms (+ fp16 conversions) ----------------

__global__ __launch_bounds__(256) void prep_z_k(const float* __restrict__ z,
                                                float* __restrict__ zinv,
                                                int* __restrict__ fcnt) {
    if (blockIdx.x == 0 && threadIdx.x == 0) *fcnt = 0;
    int row = blockIdx.x * 4 + (threadIdx.x >> 6);
    int lane = threadIdx.x & 63;
    const float4* p = reinterpret_cast<const float4*>(z + (size_t)row * H_DIM);
    float4 a = p[lane * 2];
    float4 b = p[lane * 2 + 1];
    float s = a.x * a.x + a.y * a.y + a.z * a.z + a.w * a.w
            + b.x * b.x + b.y * b.y + b.z * b.z + b.w * b.w;
#pragma unroll
    for (int m = 32; m >= 1; m >>= 1) s += __shfl_xor(s, m, 64);
    if (lane == 0) zinv[row] = 1.0f / fmaxf(sqrtf(s), 1e-12f);
}

// minv + normalized fp16 rows, XOR-swizzled within each 128B window
__global__ __launch_bounds__(256) void prep_mem_k(const float* __restrict__ mem,
                                                  float* __restrict__ minv,
                                                  short* __restrict__ mn_sw) {
    int row = blockIdx.x * 4 + (threadIdx.x >> 6);
    int lane = threadIdx.x & 63;
    const float4* p = reinterpret_cast<const float4*>(mem + (size_t)row * H_DIM);
    float4 a = p[lane * 2];
    float4 b = p[lane * 2 + 1];
    float s = a.x * a.x + a.y * a.y + a.z * a.z + a.w * a.w
            + b.x * b.x + b.y * b.y + b.z * b.z + b.w * b.w;
#pragma unroll
    for (int m = 32; m >= 1; m >>= 1) s += __shfl_xor(s, m, 64);
    float inv = 1.0f / fmaxf(sqrtf(s), 1e-12f);
    if (lane == 0) minv[row] = inv;
    uint4 w;
    w.x = pk2h(a.x * inv, a.y * inv);
    w.y = pk2h(a.z * inv, a.w * inv);
    w.z = pk2h(b.x * inv, b.y * inv);
    w.w = pk2h(b.z * inv, b.w * inv);
    char* dst = (char*)mn_sw + ((size_t)row << 10) + ((unsigned)(lane * 16) ^ (unsigned)((row & 7) << 4));
    *reinterpret_cast<uint4*>(dst) = w;
}

// raw mem transposed to [H][N] fp16, XOR-swizzled within each 128B window
__global__ __launch_bounds__(256) void prep_memT_k(const float* __restrict__ mem,
                                                   short* __restrict__ memT_sw) {
    __shared__ short Ts[64][72];
    int bs = blockIdx.x;          // slot tile (32)
    int bh = blockIdx.y;          // h tile (8)
    int tid = threadIdx.x;
    {
        int s = tid >> 2, c4 = (tid & 3) * 16;
        const float* src = mem + (size_t)(bs * 64 + s) * H_DIM + bh * 64 + c4;
#pragma unroll
        for (int j = 0; j < 4; ++j) {
            float4 v = *reinterpret_cast<const float4*>(src + j * 4);
            Ts[s][c4 + j * 4 + 0] = (short)f2h(v.x);
            Ts[s][c4 + j * 4 + 1] = (short)f2h(v.y);
            Ts[s][c4 + j * 4 + 2] = (short)f2h(v.z);
            Ts[s][c4 + j * 4 + 3] = (short)f2h(v.w);
        }
    }
    __syncthreads();
    int h = tid >> 2, q = tid & 3;
    unsigned w[8];
#pragma unroll
    for (int k = 0; k < 8; ++k) {
        unsigned lo = (unsigned short)Ts[q * 16 + 2 * k][h];
        unsigned hi = (unsigned short)Ts[q * 16 + 2 * k + 1][h];
        w[k] = lo | (hi << 16);
    }
    uint4 c0 = {w[0], w[1], w[2], w[3]};
    uint4 c1 = {w[4], w[5], w[6], w[7]};
    char* dst = (char*)memT_sw + (size_t)(bh * 64 + h) * (N_SLOTS * 2);
    unsigned sw = (unsigned)((h & 7) << 4);
    unsigned b0 = (unsigned)(bs * 128 + q * 32);
    *reinterpret_cast<uint4*>(dst + (b0 ^ sw)) = c0;
    *reinterpret_cast<uint4*>(dst + ((b0 + 16) ^ sw)) = c1;
}

// ---------------- fused zhat: counted-vmcnt pipeline, 2x reuse in BOTH QK and PV ----------------

__global__ __launch_bounds__(512, 2) void zhat_k(const float* __restrict__ z,
                                                 const short* __restrict__ mn_sw,
                                                 const short* __restrict__ memT_sw,
                                                 const float* __restrict__ zinv,
                                                 float* __restrict__ rowmax,
                                                 int* __restrict__ rowarg,
                                                 float* __restrict__ rowm2,
                                                 float* __restrict__ out) {
    __shared__ __align__(16) short Mb[4][8192];      // 4 x 16KB rotation (M [128][64] / V [64][128])
    __shared__ __align__(16) short Pl[64 * ZPL];     // P [64 rows][128 slots] padded
    __shared__ float pm1[4][64], pm2[4][64], ps[4][64];
    __shared__ int pa1[4][64];

    int tid = threadIdx.x;
    int row0 = blockIdx.x * 64;
    int wave = tid >> 6, lane = tid & 63;
    int lm = lane & 15, quad = lane >> 4;
    int rq = wave & 1;          // row-tile pair {2rq, 2rq+1} (QK and PV)
    int wq = wave >> 1;         // QK: 32-slot quarter; PV: 16-h tile per 64-h chunk
    const int swz = (lm & 7) << 4;

    // M-tile stage: 128 rows x 128B (pre-swizzled rows copied linearly); 2 loads/wave
#define STAGE_M(buf, c0, kc) do { \
        const char* _g = (const char*)mn_sw + ((size_t)((c0) + wave * 16 + (lane >> 3)) << 10) \
                         + ((kc) << 7) + ((lane & 7) << 4); \
        short* _l = &Mb[buf][wave * 16 * 64]; \
        STAGE16(_g, _l); \
        STAGE16(_g + (8 << 10), _l + 8 * 64); \
    } while (0)

    // V-tile stage: 64 h-rows x 256B segment of memT; 2 loads/wave
#define STAGE_V(buf, c0, hc) do { \
        const char* _g = (const char*)memT_sw + ((size_t)((hc) * 64 + wave * 8 + (lane >> 4)) << 12) \
                         + ((size_t)(c0) << 1) + ((lane & 15) << 4); \
        short* _l = &Mb[buf][wave * 8 * 128]; \
        STAGE16(_g, _l); \
        STAGE16(_g + (4 << 12), _l + 4 * 128); \
    } while (0)

    // prologue: stage first two M-tiles (depth-2 pipeline)
    STAGE_M(0, 0, 0);
    STAGE_M(1, 0, 1);

    // Z fragments for BOTH owned row-tiles (reused across all 16 ct)
    f16x8 Zfr[2][16];
#pragma unroll
    for (int rtl = 0; rtl < 2; ++rtl) {
        int zrow = row0 + (rq * 2 + rtl) * 16 + lm;
        float zi = zinv[zrow];
#pragma unroll
        for (int kt = 0; kt < 16; ++kt) {
            const float* zp = z + (size_t)zrow * H_DIM + kt * 32 + quad * 8;
            float4 a = *reinterpret_cast<const float4*>(zp);
            float4 b = *reinterpret_cast<const float4*>(zp + 4);
            union { uint4 u; f16x8 v; } cv;
            cv.u.x = pk2h(a.x * zi, a.y * zi);
            cv.u.y = pk2h(a.z * zi, a.w * zi);
            cv.u.z = pk2h(b.x * zi, b.y * zi);
            cv.u.w = pk2h(b.z * zi, b.w * zi);
            Zfr[rtl][kt] = cv.v;
        }
    }

    f32x4 acc[16];
#pragma unroll
    for (int t = 0; t < 16; ++t) acc[t] = (f32x4){0.f, 0.f, 0.f, 0.f};
    float rm1[2][4], rm2[2][4], lsum[2][4];
    int ra1[2][4];
#pragma unroll
    for (int rtl = 0; rtl < 2; ++rtl)
#pragma unroll
        for (int r = 0; r < 4; ++r) {
            rm1[rtl][r] = -3.4e38f; rm2[rtl][r] = -3.4e38f;
            lsum[rtl][r] = 0.f; ra1[rtl][r] = 0;
        }

    for (int ct = 0; ct < 16; ++ct) {
        int col0 = ct * 128;
        int col0n = (ct < 15) ? col0 + 128 : 0;   // ct=15: dummy re-stage (never read)
        f32x4 sacc[2][2];
#pragma unroll
        for (int rtl = 0; rtl < 2; ++rtl)
#pragma unroll
            for (int i = 0; i < 2; ++i) sacc[rtl][i] = (f32x4){0.f, 0.f, 0.f, 0.f};

        // ---- QK: 8 K-steps; stage(t+2) || compute(t); each M-frag feeds 2 row-tiles ----
#pragma unroll
        for (int kc = 0; kc < 8; ++kc) {
            if (kc < 6)       STAGE_M((kc + 2) & 3, col0, kc + 2);
            else if (kc == 6) STAGE_V(0, col0, 0);
            else              STAGE_V(1, col0, 1);
            VWAIT4();                    // tile kc landed; kc+1/kc+2 stay in flight
            __builtin_amdgcn_s_barrier();
            __builtin_amdgcn_s_setprio(1);
#pragma unroll
            for (int ks = 0; ks < 2; ++ks) {
#pragma unroll
                for (int i = 0; i < 2; ++i) {
                    int srow = (wq * 2 + i) * 16 + lm;
                    int kb = (ks * 64 + quad * 16) ^ swz;
                    f16x8 bfr = *reinterpret_cast<const f16x8*>(
                        (const char*)&Mb[kc & 3][0] + srow * 128 + kb);
                    sacc[0][i] = __builtin_amdgcn_mfma_f32_16x16x32_f16(Zfr[0][kc * 2 + ks], bfr, sacc[0][i], 0, 0, 0);
                    sacc[1][i] = __builtin_amdgcn_mfma_f32_16x16x32_f16(Zfr[1][kc * 2 + ks], bfr, sacc[1][i], 0, 0, 0);
                }
            }
            __builtin_amdgcn_s_setprio(0);
        }

        // ---- softmax (|sim|<=1: no max subtraction) + running top-2 (value-only m2) + P write ----
#pragma unroll
        for (int rtl = 0; rtl < 2; ++rtl)
#pragma unroll
            for (int i = 0; i < 2; ++i) {
                int sl = wq * 32 + i * 16 + lm;
                int sg = col0 + sl;
#pragma unroll
                for (int r = 0; r < 4; ++r) {
                    float v = sacc[rtl][i][r];
                    if (v > rm1[rtl][r]) { rm2[rtl][r] = rm1[rtl][r]; rm1[rtl][r] = v; ra1[rtl][r] = sg; }
                    else if (v > rm2[rtl][r]) rm2[rtl][r] = v;
                    float p = __expf(v);
                    lsum[rtl][r] += p;
                    Pl[((rq * 2 + rtl) * 16 + quad * 4 + r) * ZPL + sl] = (short)f2h(p);
                }
            }
        LWAIT0();                        // Pl writes visible; V0/V1 stages stay in flight
        __builtin_amdgcn_s_barrier();

        // hoisted PV A-fragments for BOTH owned row-tiles (read once per ct)
        f16x8 pa_all[2][4];
#pragma unroll
        for (int rtl = 0; rtl < 2; ++rtl)
#pragma unroll
            for (int ks = 0; ks < 4; ++ks)
                pa_all[rtl][ks] = *reinterpret_cast<const f16x8*>(
                    &Pl[((rq * 2 + rtl) * 16 + lm) * ZPL + ks * 32 + quad * 8]);

        // ---- PV: 8 h-steps; stage(t+2) || compute(t); each V-frag feeds 2 row-tiles ----
#pragma unroll
        for (int hc = 0; hc < 8; ++hc) {
            if (hc < 6)       STAGE_V((hc + 2) & 3, col0, hc + 2);
            else if (hc == 6) STAGE_M(0, col0n, 0);
            else              STAGE_M(1, col0n, 1);
            VWAIT4();
            __builtin_amdgcn_s_barrier();
            __builtin_amdgcn_s_setprio(1);
#pragma unroll
            for (int ks = 0; ks < 4; ++ks) {
                int hl = wq * 16 + lm;
                int kb = (ks * 64 + quad * 16) ^ swz;
                f16x8 vf = *reinterpret_cast<const f16x8*>(
                    (const char*)&Mb[hc & 3][0] + hl * 256 + kb);
                acc[hc * 2 + 0] = __builtin_amdgcn_mfma_f32_16x16x32_f16(pa_all[0][ks], vf, acc[hc * 2 + 0], 0, 0, 0);
                acc[hc * 2 + 1] = __builtin_amdgcn_mfma_f32_16x16x32_f16(pa_all[1][ks], vf, acc[hc * 2 + 1], 0, 0, 0);
            }
            __builtin_amdgcn_s_setprio(0);
        }
    }
    __syncthreads();   // full drain (dummy stages) before epilogue LDS reuse

    // ---- final merges: 16-lane butterfly (disjoint 32-slot subsets), then 4-way wq merge ----
#pragma unroll
    for (int mk = 1; mk < 16; mk <<= 1) {
#pragma unroll
        for (int rtl = 0; rtl < 2; ++rtl)
#pragma unroll
            for (int r = 0; r < 4; ++r) {
                float n1 = __shfl_xor(rm1[rtl][r], mk, 16);
                int b1 = __shfl_xor(ra1[rtl][r], mk, 16);
                float n2 = __shfl_xor(rm2[rtl][r], mk, 16);
                if (n1 > rm1[rtl][r]) {
                    rm2[rtl][r] = fmaxf(rm1[rtl][r], n2);
                    rm1[rtl][r] = n1; ra1[rtl][r] = b1;
                } else {
                    rm2[rtl][r] = fmaxf(rm2[rtl][r], n1);
                }
                lsum[rtl][r] += __shfl_xor(lsum[rtl][r], mk, 16);
            }
    }
    if (lm == 0) {
#pragma unroll
        for (int rtl = 0; rtl < 2; ++rtl)
#pragma unroll
            for (int r = 0; r < 4; ++r) {
                int rl = (rq * 2 + rtl) * 16 + quad * 4 + r;
                pm1[wq][rl] = rm1[rtl][r]; pa1[wq][rl] = ra1[rtl][r];
                pm2[wq][rl] = rm2[rtl][r]; ps[wq][rl] = lsum[rtl][r];
            }
    }
    __syncthreads();
    if (wave == 0) {
        int r = lane;
        float gm1 = pm1[0][r], gm2 = pm2[0][r];
        int ga1 = pa1[0][r];
#pragma unroll
        for (int w2 = 1; w2 < 4; ++w2) {
            float n1 = pm1[w2][r], n2 = pm2[w2][r];
            int b1 = pa1[w2][r];
            if (n1 > gm1) { gm2 = fmaxf(gm1, n2); gm1 = n1; ga1 = b1; }
            else          { gm2 = fmaxf(gm2, n1); }
        }
        rowmax[row0 + r] = gm1; rowarg[row0 + r] = ga1; rowm2[row0 + r] = gm2;
    }
    float linv2[2][4];
#pragma unroll
    for (int rtl = 0; rtl < 2; ++rtl)
#pragma unroll
        for (int r = 0; r < 4; ++r) {
            int rl = (rq * 2 + rtl) * 16 + quad * 4 + r;
            linv2[rtl][r] = 1.0f / ((ps[0][rl] + ps[1][rl]) + (ps[2][rl] + ps[3][rl]));
        }
#pragma unroll
    for (int hc = 0; hc < 8; ++hc)
#pragma unroll
        for (int rtl = 0; rtl < 2; ++rtl) {
            int t = hc * 2 + rtl;
            int h = hc * 64 + wq * 16 + lm;
#pragma unroll
            for (int r = 0; r < 4; ++r) {
                int rg = row0 + (rq * 2 + rtl) * 16 + quad * 4 + r;
                out[(size_t)rg * H_DIM + h] = acc[t][r] * linv2[rtl][r];
            }
        }
}

// ---------------- flag near-tie rows into a compact worklist ----------------

__global__ __launch_bounds__(256) void flag_k(const float* __restrict__ rowmax,
                                              const float* __restrict__ rowm2,
                                              int* __restrict__ cnt,
                                              int* __restrict__ list,
                                              unsigned long long* __restrict__ packed) {
    int b = blockIdx.x * 256 + threadIdx.x;
    if (rowmax[b] - rowm2[b] < FIX_MARGIN) {
        int p = atomicAdd(cnt, 1);
        list[p] = b;
        packed[p] = 0ull;
    }
}

// ---------------- exact: full fp32 argmax over all slots for flagged rows ----------------

__global__ __launch_bounds__(256) void exact_k(const float* __restrict__ z,
                                               const float* __restrict__ mem,
                                               const float* __restrict__ minv,
                                               const int* __restrict__ cnt,
                                               const int* __restrict__ list,
                                               unsigned long long* __restrict__ packed) {
    __shared__ float As[32][XROWS + 4];
    __shared__ float Bs[32][132];
    __shared__ int rows[XROWS];
    int tid = threadIdx.x;
    int tx = tid & 15, ty = tid >> 4;
    int n = *cnt;
    int ngroups = (n + XROWS - 1) / XROWS;
    int nunits = ngroups * 16;

    for (int u = blockIdx.x; u < nunits; u += gridDim.x) {
        int g = u >> 4;
        int col0 = (u & 15) * 128;
        __syncthreads();   // protect rows[] reuse across units
        if (tid < XROWS) {
            int idx = g * XROWS + tid;
            rows[tid] = list[idx < n ? idx : n - 1];
        }
        __syncthreads();
        float acc[8];
#pragma unroll
        for (int j = 0; j < 8; ++j) acc[j] = 0.f;
        for (int kc = 0; kc < H_DIM; kc += 32) {
            if (tid < 128) {
                int r = tid >> 3, k4 = (tid & 7) * 4;
                float4 v = *reinterpret_cast<const float4*>(z + (size_t)rows[r] * H_DIM + kc + k4);
                As[k4 + 0][r] = v.x;
                As[k4 + 1][r] = v.y;
                As[k4 + 2][r] = v.z;
                As[k4 + 3][r] = v.w;
            }
            int sl = tid >> 1, kq = (tid & 1) * 16;
#pragma unroll
            for (int j = 0; j < 4; ++j) {
                float4 v = *reinterpret_cast<const float4*>(mem + (size_t)(col0 + sl) * H_DIM + kc + kq + j * 4);
                Bs[kq + j * 4 + 0][sl] = v.x;
                Bs[kq + j * 4 + 1][sl] = v.y;
                Bs[kq + j * 4 + 2][sl] = v.z;
                Bs[kq + j * 4 + 3][sl] = v.w;
            }
            __syncthreads();
#pragma unroll 4
            for (int k = 0; k < 32; ++k) {
                float av = As[k][ty];
                const float4 b0 = *reinterpret_cast<const float4*>(&Bs[k][tx * 8]);
                const float4 b1 = *reinterpret_cast<const float4*>(&Bs[k][tx * 8 + 4]);
                acc[0] = fmaf(av, b0.x, acc[0]);
                acc[1] = fmaf(av, b0.y, acc[1]);
                acc[2] = fmaf(av, b0.z, acc[2]);
                acc[3] = fmaf(av, b0.w, acc[3]);
                acc[4] = fmaf(av, b1.x, acc[4]);
                acc[5] = fmaf(av, b1.y, acc[5]);
                acc[6] = fmaf(av, b1.z, acc[6]);
                acc[7] = fmaf(av, b1.w, acc[7]);
            }
            __syncthreads();
        }
        float runM = -3.4e38f;
        int runA = 0;
#pragma unroll
        for (int j = 0; j < 8; ++j) {
            int sg = col0 + tx * 8 + j;
            float s = acc[j] * minv[sg];
            if (s > runM) { runM = s; runA = sg; }
        }
#pragma unroll
        for (int mk = 1; mk < 16; mk <<= 1) {
            float om = __shfl_xor(runM, mk, 16);
            int oa = __shfl_xor(runA, mk, 16);
            if (om > runM || (om == runM && oa < runA)) { runM = om; runA = oa; }
        }
        if (tx == 0) {
            int idx = g * XROWS + ty;
            int tgt = idx < n ? idx : n - 1;
            unsigned long long pk =
                ((unsigned long long)fenc(runM) << 32) | (unsigned)(2047 - runA);
            atomicMax(&packed[tgt], pk);
        }
    }
}

__global__ __launch_bounds__(256) void unpack_k(const int* __restrict__ cnt,
                                                const int* __restrict__ list,
                                                const unsigned long long* __restrict__ packed,
                                                int* __restrict__ rowarg) {
    int p = blockIdx.x * 256 + threadIdx.x;
    if (p < *cnt) {
        int slot = 2047 - (int)(unsigned)(packed[p] & 0xFFFFFFFFull);
        rowarg[list[p]] = slot;
    }
}

// ---------------- refine: fp32 rowmax for ALL rows given final argmax ----------------

__global__ __launch_bounds__(256) void refine_k(const float* __restrict__ z,
                                                const float* __restrict__ mem,
                                                const float* __restrict__ zinv,
                                                const float* __restrict__ minv,
                                                const int* __restrict__ rowarg,
                                                float* __restrict__ rowmax) {
    int row = blockIdx.x * 4 + (threadIdx.x >> 6);
    int lane = threadIdx.x & 63;
    int a = rowarg[row];
    const float4* zp = reinterpret_cast<const float4*>(z + (size_t)row * H_DIM);
    const float4* mp = reinterpret_cast<const float4*>(mem + (size_t)a * H_DIM);
    float d = 0.f;
#pragma unroll
    for (int j = 0; j < 2; ++j) {
        float4 x = zp[lane + j * 64];
        float4 y = mp[lane + j * 64];
        d += x.x * y.x + x.y * y.y + x.z * y.z + x.w * y.w;
    }
#pragma unroll
    for (int m = 32; m >= 1; m >>= 1) d += __shfl_xor(d, m, 64);
    if (lane == 0) rowmax[row] = d * zinv[row] * minv[a];
}

// ---------------- per-slot update: gather members, masked softmax, renormalize ----------------

__global__ __launch_bounds__(256) void slot_update_k(const float* __restrict__ mem,
                                                     const float* __restrict__ z,
                                                     const float* __restrict__ rowmax,
                                                     const int* __restrict__ rowarg,
                                                     float* __restrict__ outmem) {
    __shared__ int members[MCAP];
    __shared__ float uval[MCAP];
    __shared__ int cnt;
    __shared__ float red[4];
    __shared__ float bcast;
    int slot = blockIdx.x, tid = threadIdx.x;
    if (tid == 0) cnt = 0;
    __syncthreads();
    for (int b = tid; b < B_ROWS; b += 256) {
        if (rowarg[b] == slot) {
            int p = atomicAdd(&cnt, 1);
            if (p < MCAP) members[p] = b;
        }
    }
    __syncthreads();
    int n = min(cnt, MCAP);
    size_t base = (size_t)slot * H_DIM;
    if (n == 0) {
        for (int h = tid; h < H_DIM; h += 256) outmem[base + h] = mem[base + h];
        return;
    }
    float lm = -3.4e38f;
    for (int j = tid; j < n; j += 256) lm = fmaxf(lm, rowmax[members[j]]);
#pragma unroll
    for (int m = 32; m >= 1; m >>= 1) lm = fmaxf(lm, __shfl_xor(lm, m, 64));
    if ((tid & 63) == 0) red[tid >> 6] = lm;
    __syncthreads();
    if (tid == 0) bcast = fmaxf(fmaxf(red[0], red[1]), fmaxf(red[2], red[3]));
    __syncthreads();
    float mslot = bcast;
    __syncthreads();
    float ls = 0.f;
    for (int j = tid; j < n; j += 256) {
        float u = expf(rowmax[members[j]] - mslot);
        uval[j] = u;
        ls += u;
    }
#pragma unroll
    for (int m = 32; m >= 1; m >>= 1) ls += __shfl_xor(ls, m, 64);
    if ((tid & 63) == 0) red[tid >> 6] = ls;
    __syncthreads();
    if (tid == 0) bcast = (red[0] + red[1]) + (red[2] + red[3]);
    __syncthreads();
    float dinv = 1.0f / fmaxf(bcast, 1e-30f);
    float v0 = mem[base + tid];
    float v1 = mem[base + 256 + tid];
    for (int j = 0; j < n; ++j) {
        float u = uval[j] * dinv;
        size_t zb = (size_t)members[j] * H_DIM;
        v0 = fmaf(u, z[zb + tid], v0);
        v1 = fmaf(u, z[zb + 256 + tid], v1);
    }
    float s = v0 * v0 + v1 * v1;
#pragma unroll
    for (int m = 32; m >= 1; m >>= 1) s += __shfl_xor(s, m, 64);
    if ((tid & 63) == 0) red[tid >> 6] = s;
    __syncthreads();
    if (tid == 0) bcast = (red[0] + red[1]) + (red[2] + red[3]);
    __syncthreads();
    float ninv = 1.0f / fmaxf(sqrtf(bcast), 1e-12f);
    outmem[base + tid] = v0 * ninv;
    outmem[base + 256 + tid] = v1 * ninv;
}

// ---------------- launch ----------------

extern "C" void kernel_launch(void* const* d_in, const int* in_sizes, int n_in,
                              void* d_out, int out_size, void* d_ws, size_t ws_size,
                              hipStream_t stream) {
    const float* z = (const float*)d_in[0];
    const float* mem = (const float*)d_in[1];
    float* out_zhat = (float*)d_out;
    float* out_mem = out_zhat + (size_t)B_ROWS * H_DIM;

    char* ws = (char*)d_ws;
    size_t off = 0;
    auto alloc = [&](size_t bytes) -> void* {
        void* p = ws + off;
        off += (bytes + 255) & ~(size_t)255;
        return p;
    };
    float* rowmax = (float*)alloc((size_t)B_ROWS * 4);
    int* rowarg = (int*)alloc((size_t)B_ROWS * 4);
    float* rowm2 = (float*)alloc((size_t)B_ROWS * 4);
    float* zinv = (float*)alloc((size_t)B_ROWS * 4);
    float* minv = (float*)alloc((size_t)N_SLOTS * 4);
    short* mn_sw = (short*)alloc((size_t)N_SLOTS * H_DIM * 2);
    short* memT_sw = (short*)alloc((size_t)H_DIM * N_SLOTS * 2);
    int* fcnt = (int*)alloc(256);
    int* flist = (int*)alloc((size_t)B_ROWS * 4);
    unsigned long long* packed = (unsigned long long*)alloc((size_t)B_ROWS * 8);

    prep_z_k<<<B_ROWS / 4, 256, 0, stream>>>(z, zinv, fcnt);
    prep_mem_k<<<N_SLOTS / 4, 256, 0, stream>>>(mem, minv, mn_sw);
    prep_memT_k<<<dim3(N_SLOTS / 64, H_DIM / 64), 256, 0, stream>>>(mem, memT_sw);
    zhat_k<<<B_ROWS / 64, 512, 0, stream>>>(z, mn_sw, memT_sw, zinv,
                                            rowmax, rowarg, rowm2, out_zhat);
    flag_k<<<B_ROWS / 256, 256, 0, stream>>>(rowmax, rowm2, fcnt, flist, packed);
    exact_k<<<2048, 256, 0, stream>>>(z, mem, minv, fcnt, flist, packed);
    unpack_k<<<B_ROWS / 256, 256, 0, stream>>>(fcnt, flist, packed, rowarg);
    refine_k<<<B_ROWS / 4, 256, 0, stream>>>(z, mem, zinv, minv, rowarg, rowmax);
    slot_update_k<<<N_SLOTS, 256, 0, stream>>>(mem, z, rowmax, rowarg, out_mem);
}

// Round 8
// 563.799 us; speedup vs baseline: 1.1171x; 1.1171x over previous
//
#include <hip/hip_runtime.h>
#include <math.h>

#define B_ROWS 32768
#define N_SLOTS 2048
#define H_DIM 512
#define MCAP 4096

typedef __attribute__((ext_vector_type(8))) _Float16 f16x8;
typedef __attribute__((ext_vector_type(4))) float f32x4;

#define ZPL 132   // Pl stride (shorts)
#define FIX_MARGIN 2.5e-4f   // fp16 sims: gap-error sigma ~5e-5 -> 4.6 sigma margin
#define XROWS 16

__device__ __forceinline__ unsigned short f2h(float f) {
    union { _Float16 h; unsigned short u; } cv;
    cv.h = (_Float16)f;          // v_cvt_f16_f32, RTN
    return cv.u;
}
__device__ __forceinline__ unsigned pk2h(float a, float b) {
    return (unsigned)f2h(a) | ((unsigned)f2h(b) << 16);
}
// monotonic float->uint encode: a > b  <=>  fenc(a) > fenc(b)
__device__ __forceinline__ unsigned fenc(float f) {
    unsigned b = __float_as_uint(f);
    return (b & 0x80000000u) ? ~b : (b | 0x80000000u);
}

// async global->LDS, 16B per lane, LDS dest = wave-uniform base + lane*16
#define STAGE16(g, l) __builtin_amdgcn_global_load_lds( \
    (const __attribute__((address_space(1))) unsigned int*)(g), \
    (__attribute__((address_space(3))) unsigned int*)(l), 16, 0, 0)

// counted waits + raw barrier (T4): keep prefetch in flight across barriers
#define VWAIT4() asm volatile("s_waitcnt vmcnt(4)" ::: "memory")
#define LWAIT0() asm volatile("s_waitcnt lgkmcnt(0)" ::: "memory")

// ---------------- prep: reciprocal norms (+ fp16 conversions) ----------------

__global__ __launch_bounds__(256) void prep_z_k(const float* __restrict__ z,
                                                float* __restrict__ zinv,
                                                int* __restrict__ fcnt) {
    if (blockIdx.x == 0 && threadIdx.x == 0) *fcnt = 0;
    int row = blockIdx.x * 4 + (threadIdx.x >> 6);
    int lane = threadIdx.x & 63;
    const float4* p = reinterpret_cast<const float4*>(z + (size_t)row * H_DIM);
    float4 a = p[lane * 2];
    float4 b = p[lane * 2 + 1];
    float s = a.x * a.x + a.y * a.y + a.z * a.z + a.w * a.w
            + b.x * b.x + b.y * b.y + b.z * b.z + b.w * b.w;
#pragma unroll
    for (int m = 32; m >= 1; m >>= 1) s += __shfl_xor(s, m, 64);
    if (lane == 0) zinv[row] = 1.0f / fmaxf(sqrtf(s), 1e-12f);
}

// minv + normalized fp16 rows, XOR-swizzled within each 128B window
__global__ __launch_bounds__(256) void prep_mem_k(const float* __restrict__ mem,
                                                  float* __restrict__ minv,
                                                  short* __restrict__ mn_sw) {
    int row = blockIdx.x * 4 + (threadIdx.x >> 6);
    int lane = threadIdx.x & 63;
    const float4* p = reinterpret_cast<const float4*>(mem + (size_t)row * H_DIM);
    float4 a = p[lane * 2];
    float4 b = p[lane * 2 + 1];
    float s = a.x * a.x + a.y * a.y + a.z * a.z + a.w * a.w
            + b.x * b.x + b.y * b.y + b.z * b.z + b.w * b.w;
#pragma unroll
    for (int m = 32; m >= 1; m >>= 1) s += __shfl_xor(s, m, 64);
    float inv = 1.0f / fmaxf(sqrtf(s), 1e-12f);
    if (lane == 0) minv[row] = inv;
    uint4 w;
    w.x = pk2h(a.x * inv, a.y * inv);
    w.y = pk2h(a.z * inv, a.w * inv);
    w.z = pk2h(b.x * inv, b.y * inv);
    w.w = pk2h(b.z * inv, b.w * inv);
    char* dst = (char*)mn_sw + ((size_t)row << 10) + ((unsigned)(lane * 16) ^ (unsigned)((row & 7) << 4));
    *reinterpret_cast<uint4*>(dst) = w;
}

// raw mem transposed to [H][N] fp16, XOR-swizzled within each 128B window
__global__ __launch_bounds__(256) void prep_memT_k(const float* __restrict__ mem,
                                                   short* __restrict__ memT_sw) {
    __shared__ short Ts[64][72];
    int bs = blockIdx.x;          // slot tile (32)
    int bh = blockIdx.y;          // h tile (8)
    int tid = threadIdx.x;
    {
        int s = tid >> 2, c4 = (tid & 3) * 16;
        const float* src = mem + (size_t)(bs * 64 + s) * H_DIM + bh * 64 + c4;
#pragma unroll
        for (int j = 0; j < 4; ++j) {
            float4 v = *reinterpret_cast<const float4*>(src + j * 4);
            Ts[s][c4 + j * 4 + 0] = (short)f2h(v.x);
            Ts[s][c4 + j * 4 + 1] = (short)f2h(v.y);
            Ts[s][c4 + j * 4 + 2] = (short)f2h(v.z);
            Ts[s][c4 + j * 4 + 3] = (short)f2h(v.w);
        }
    }
    __syncthreads();
    int h = tid >> 2, q = tid & 3;
    unsigned w[8];
#pragma unroll
    for (int k = 0; k < 8; ++k) {
        unsigned lo = (unsigned short)Ts[q * 16 + 2 * k][h];
        unsigned hi = (unsigned short)Ts[q * 16 + 2 * k + 1][h];
        w[k] = lo | (hi << 16);
    }
    uint4 c0 = {w[0], w[1], w[2], w[3]};
    uint4 c1 = {w[4], w[5], w[6], w[7]};
    char* dst = (char*)memT_sw + (size_t)(bh * 64 + h) * (N_SLOTS * 2);
    unsigned sw = (unsigned)((h & 7) << 4);
    unsigned b0 = (unsigned)(bs * 128 + q * 32);
    *reinterpret_cast<uint4*>(dst + (b0 ^ sw)) = c0;
    *reinterpret_cast<uint4*>(dst + ((b0 + 16) ^ sw)) = c1;
}

// ---------------- fused zhat: counted-vmcnt 4-buffer pipeline, PV 2x V-reuse (R6 proven) ----------------

__global__ __launch_bounds__(512, 2) void zhat_k(const float* __restrict__ z,
                                                 const short* __restrict__ mn_sw,
                                                 const short* __restrict__ memT_sw,
                                                 const float* __restrict__ zinv,
                                                 float* __restrict__ rowmax,
                                                 int* __restrict__ rowarg,
                                                 float* __restrict__ rowm2,
                                                 float* __restrict__ out) {
    __shared__ __align__(16) short Mb[4][8192];      // 4 x 16KB rotation (M [128][64] / V [64][128])
    __shared__ __align__(16) short Pl[64 * ZPL];     // P [64 rows][128 slots] padded
    __shared__ float pm1[2][64], pm2[2][64], ps[2][64];
    __shared__ int pa1[2][64], pa2[2][64];

    int tid = threadIdx.x;
    int row0 = blockIdx.x * 64;
    int wave = tid >> 6, lane = tid & 63;
    int lm = lane & 15, quad = lane >> 4;
    int rt = wave & 3;          // QK wave mapping: 16 rows x 64 slots
    int wg = wave >> 2;
    int rh = wave & 1;          // PV wave mapping: 32 rows (pair of row-tiles) x 16 h per chunk
    int wc = wave >> 1;         // h-tile within 64-h chunk
    const int swz = (lm & 7) << 4;

    // M-tile stage: 128 rows x 128B (pre-swizzled rows copied linearly); 2 loads/wave
#define STAGE_M(buf, c0, kc) do { \
        const char* _g = (const char*)mn_sw + ((size_t)((c0) + wave * 16 + (lane >> 3)) << 10) \
                         + ((kc) << 7) + ((lane & 7) << 4); \
        short* _l = &Mb[buf][wave * 16 * 64]; \
        STAGE16(_g, _l); \
        STAGE16(_g + (8 << 10), _l + 8 * 64); \
    } while (0)

    // V-tile stage: 64 h-rows x 256B segment of memT; 2 loads/wave
#define STAGE_V(buf, c0, hc) do { \
        const char* _g = (const char*)memT_sw + ((size_t)((hc) * 64 + wave * 8 + (lane >> 4)) << 12) \
                         + ((size_t)(c0) << 1) + ((lane & 15) << 4); \
        short* _l = &Mb[buf][wave * 8 * 128]; \
        STAGE16(_g, _l); \
        STAGE16(_g + (4 << 12), _l + 4 * 128); \
    } while (0)

    // prologue: stage first two M-tiles (depth-2 pipeline)
    STAGE_M(0, 0, 0);
    STAGE_M(1, 0, 1);

    int zrow = row0 + rt * 16 + lm;
    float zi = zinv[zrow];
    f16x8 Zfr[16];
#pragma unroll
    for (int kt = 0; kt < 16; ++kt) {
        const float* zp = z + (size_t)zrow * H_DIM + kt * 32 + quad * 8;
        float4 a = *reinterpret_cast<const float4*>(zp);
        float4 b = *reinterpret_cast<const float4*>(zp + 4);
        union { uint4 u; f16x8 v; } cv;
        cv.u.x = pk2h(a.x * zi, a.y * zi);
        cv.u.y = pk2h(a.z * zi, a.w * zi);
        cv.u.z = pk2h(b.x * zi, b.y * zi);
        cv.u.w = pk2h(b.z * zi, b.w * zi);
        Zfr[kt] = cv.v;
    }

    f32x4 acc[16];
#pragma unroll
    for (int t = 0; t < 16; ++t) acc[t] = (f32x4){0.f, 0.f, 0.f, 0.f};
    float rm1[4], rm2[4], lsum[4];
    int ra1[4], ra2[4];
#pragma unroll
    for (int r = 0; r < 4; ++r) {
        rm1[r] = -3.4e38f; rm2[r] = -3.4e38f; lsum[r] = 0.f; ra1[r] = 0; ra2[r] = 0;
    }

    for (int ct = 0; ct < 16; ++ct) {
        int col0 = ct * 128;
        int col0n = (ct < 15) ? col0 + 128 : 0;   // ct=15: dummy re-stage (never read)
        f32x4 sacc[4];
#pragma unroll
        for (int i = 0; i < 4; ++i) sacc[i] = (f32x4){0.f, 0.f, 0.f, 0.f};

        // ---- QK: 8 K-steps; stage(t+2) || compute(t); counted vmcnt ----
#pragma unroll
        for (int kc = 0; kc < 8; ++kc) {
            if (kc < 6)       STAGE_M((kc + 2) & 3, col0, kc + 2);
            else if (kc == 6) STAGE_V(0, col0, 0);
            else              STAGE_V(1, col0, 1);
            VWAIT4();                    // tile kc landed; kc+1/kc+2 stay in flight
            __builtin_amdgcn_s_barrier();
            __builtin_amdgcn_s_setprio(1);
#pragma unroll
            for (int ks = 0; ks < 2; ++ks) {
                f16x8 af = Zfr[kc * 2 + ks];
#pragma unroll
                for (int i = 0; i < 4; ++i) {
                    int srow = (wg * 4 + i) * 16 + lm;
                    int kb = (ks * 64 + quad * 16) ^ swz;
                    f16x8 bfr = *reinterpret_cast<const f16x8*>(
                        (const char*)&Mb[kc & 3][0] + srow * 128 + kb);
                    sacc[i] = __builtin_amdgcn_mfma_f32_16x16x32_f16(af, bfr, sacc[i], 0, 0, 0);
                }
            }
            __builtin_amdgcn_s_setprio(0);
        }

        // ---- softmax (|sim|<=1: no max subtraction) + running top-2 + P write ----
#pragma unroll
        for (int i = 0; i < 4; ++i) {
            int sl = (wg * 4 + i) * 16 + lm;
            int sg = col0 + sl;
#pragma unroll
            for (int r = 0; r < 4; ++r) {
                float v = sacc[i][r];
                if (v > rm1[r]) { rm2[r] = rm1[r]; ra2[r] = ra1[r]; rm1[r] = v; ra1[r] = sg; }
                else if (v > rm2[r]) { rm2[r] = v; ra2[r] = sg; }
                float p = __expf(v);
                lsum[r] += p;
                Pl[(rt * 16 + quad * 4 + r) * ZPL + sl] = (short)f2h(p);
            }
        }
        LWAIT0();                        // Pl writes visible; V0/V1 stages stay in flight
        __builtin_amdgcn_s_barrier();

        // hoisted PV A-fragments for BOTH owned row-tiles (read once per ct)
        f16x8 pa_all[2][4];
#pragma unroll
        for (int rtl = 0; rtl < 2; ++rtl)
#pragma unroll
            for (int ks = 0; ks < 4; ++ks)
                pa_all[rtl][ks] = *reinterpret_cast<const f16x8*>(
                    &Pl[((rh * 2 + rtl) * 16 + lm) * ZPL + ks * 32 + quad * 8]);

        // ---- PV: 8 h-steps; stage(t+2) || compute(t); each V-frag feeds 2 row-tiles ----
#pragma unroll
        for (int hc = 0; hc < 8; ++hc) {
            if (hc < 6)       STAGE_V((hc + 2) & 3, col0, hc + 2);
            else if (hc == 6) STAGE_M(0, col0n, 0);
            else              STAGE_M(1, col0n, 1);
            VWAIT4();
            __builtin_amdgcn_s_barrier();
            __builtin_amdgcn_s_setprio(1);
#pragma unroll
            for (int ks = 0; ks < 4; ++ks) {
                int hl = wc * 16 + lm;
                int kb = (ks * 64 + quad * 16) ^ swz;
                f16x8 vf = *reinterpret_cast<const f16x8*>(
                    (const char*)&Mb[hc & 3][0] + hl * 256 + kb);
                acc[hc * 2 + 0] = __builtin_amdgcn_mfma_f32_16x16x32_f16(pa_all[0][ks], vf, acc[hc * 2 + 0], 0, 0, 0);
                acc[hc * 2 + 1] = __builtin_amdgcn_mfma_f32_16x16x32_f16(pa_all[1][ks], vf, acc[hc * 2 + 1], 0, 0, 0);
            }
            __builtin_amdgcn_s_setprio(0);
        }
    }
    __syncthreads();   // full drain (dummy stages) before epilogue LDS reuse

    // ---- final merges: 16-lane butterfly (disjoint slot subsets), then wg merge ----
#pragma unroll
    for (int mk = 1; mk < 16; mk <<= 1) {
#pragma unroll
        for (int r = 0; r < 4; ++r) {
            float n1 = __shfl_xor(rm1[r], mk, 16);
            int b1 = __shfl_xor(ra1[r], mk, 16);
            float n2 = __shfl_xor(rm2[r], mk, 16);
            int b2 = __shfl_xor(ra2[r], mk, 16);
            if (n1 > rm1[r]) {
                bool c = rm1[r] > n2;
                rm2[r] = c ? rm1[r] : n2; ra2[r] = c ? ra1[r] : b2;
                rm1[r] = n1; ra1[r] = b1;
            } else {
                bool c = n1 > rm2[r];
                rm2[r] = c ? n1 : rm2[r]; ra2[r] = c ? b1 : ra2[r];
            }
            lsum[r] += __shfl_xor(lsum[r], mk, 16);
        }
    }
    if (lm == 0) {
#pragma unroll
        for (int r = 0; r < 4; ++r) {
            int rl = rt * 16 + quad * 4 + r;
            pm1[wg][rl] = rm1[r]; pa1[wg][rl] = ra1[r];
            pm2[wg][rl] = rm2[r]; pa2[wg][rl] = ra2[r];
            ps[wg][rl] = lsum[r];
        }
    }
    __syncthreads();
    if (wave == 0) {
        int r = lane;
        float gm1 = pm1[0][r], gm2 = pm2[0][r];
        int ga1 = pa1[0][r], ga2 = pa2[0][r];
        float n1 = pm1[1][r]; int b1 = pa1[1][r];
        float n2 = pm2[1][r]; int b2 = pa2[1][r];
        if (n1 > gm1) {
            bool c = gm1 > n2;
            gm2 = c ? gm1 : n2; ga2 = c ? ga1 : b2;
            gm1 = n1; ga1 = b1;
        } else {
            bool c = n1 > gm2;
            gm2 = c ? n1 : gm2; ga2 = c ? b1 : ga2;
        }
        rowmax[row0 + r] = gm1; rowarg[row0 + r] = ga1; rowm2[row0 + r] = gm2;
    }
    float linv2[2][4];
#pragma unroll
    for (int rtl = 0; rtl < 2; ++rtl)
#pragma unroll
        for (int r = 0; r < 4; ++r) {
            int rl = (rh * 2 + rtl) * 16 + quad * 4 + r;
            linv2[rtl][r] = 1.0f / (ps[0][rl] + ps[1][rl]);
        }
#pragma unroll
    for (int hc = 0; hc < 8; ++hc)
#pragma unroll
        for (int rtl = 0; rtl < 2; ++rtl) {
            int t = hc * 2 + rtl;
            int h = hc * 64 + wc * 16 + lm;
#pragma unroll
            for (int r = 0; r < 4; ++r) {
                int rg = row0 + (rh * 2 + rtl) * 16 + quad * 4 + r;
                out[(size_t)rg * H_DIM + h] = acc[t][r] * linv2[rtl][r];
            }
        }
}

// ---------------- flag near-tie rows into a compact worklist ----------------

__global__ __launch_bounds__(256) void flag_k(const float* __restrict__ rowmax,
                                              const float* __restrict__ rowm2,
                                              int* __restrict__ cnt,
                                              int* __restrict__ list,
                                              unsigned long long* __restrict__ packed) {
    int b = blockIdx.x * 256 + threadIdx.x;
    if (rowmax[b] - rowm2[b] < FIX_MARGIN) {
        int p = atomicAdd(cnt, 1);
        list[p] = b;
        packed[p] = 0ull;
    }
}

// ---------------- exact: full fp32 argmax over all slots for flagged rows ----------------
// Parallel over (group of 16 rows) x (ct tile of 128 slots). 2 rows x 4 slots per
// thread: 1 b128 + 2 broadcast b32 LDS reads per 16 FMAs (2.5x less LDS-port time
// per FMA than 1 row x 8 slots). Same per-(row,slot) fp32 accumulation order ->
// bit-identical sims -> same argmax; min-slot tie-break preserved.

__global__ __launch_bounds__(256) void exact_k(const float* __restrict__ z,
                                               const float* __restrict__ mem,
                                               const float* __restrict__ minv,
                                               const int* __restrict__ cnt,
                                               const int* __restrict__ list,
                                               unsigned long long* __restrict__ packed) {
    __shared__ float As[32][XROWS + 4];
    __shared__ float Bs[32][132];
    __shared__ int rows[XROWS];
    int tid = threadIdx.x;
    int tx = tid & 31;        // 4-slot group (32 x 4 = 128 slots)
    int ty = tid >> 5;        // row pair: rows {ty, ty+8}
    int n = *cnt;
    int ngroups = (n + XROWS - 1) / XROWS;
    int nunits = ngroups * 16;

    for (int u = blockIdx.x; u < nunits; u += gridDim.x) {
        int g = u >> 4;
        int col0 = (u & 15) * 128;
        __syncthreads();   // protect rows[]/LDS reuse across units
        if (tid < XROWS) {
            int idx = g * XROWS + tid;
            rows[tid] = list[idx < n ? idx : n - 1];
        }
        __syncthreads();
        float acc0[4], acc1[4];
#pragma unroll
        for (int j = 0; j < 4; ++j) { acc0[j] = 0.f; acc1[j] = 0.f; }
        for (int kc = 0; kc < H_DIM; kc += 32) {
            if (tid < 128) {
                int r = tid >> 3, k4 = (tid & 7) * 4;
                float4 v = *reinterpret_cast<const float4*>(z + (size_t)rows[r] * H_DIM + kc + k4);
                As[k4 + 0][r] = v.x;
                As[k4 + 1][r] = v.y;
                As[k4 + 2][r] = v.z;
                As[k4 + 3][r] = v.w;
            }
            int sl = tid >> 1, kq = (tid & 1) * 16;
#pragma unroll
            for (int j = 0; j < 4; ++j) {
                float4 v = *reinterpret_cast<const float4*>(mem + (size_t)(col0 + sl) * H_DIM + kc + kq + j * 4);
                Bs[kq + j * 4 + 0][sl] = v.x;
                Bs[kq + j * 4 + 1][sl] = v.y;
                Bs[kq + j * 4 + 2][sl] = v.z;
                Bs[kq + j * 4 + 3][sl] = v.w;
            }
            __syncthreads();
#pragma unroll 8
            for (int k = 0; k < 32; ++k) {
                float a0 = As[k][ty];
                float a1 = As[k][ty + 8];
                const float4 b = *reinterpret_cast<const float4*>(&Bs[k][tx * 4]);
                acc0[0] = fmaf(a0, b.x, acc0[0]);
                acc0[1] = fmaf(a0, b.y, acc0[1]);
                acc0[2] = fmaf(a0, b.z, acc0[2]);
                acc0[3] = fmaf(a0, b.w, acc0[3]);
                acc1[0] = fmaf(a1, b.x, acc1[0]);
                acc1[1] = fmaf(a1, b.y, acc1[1]);
                acc1[2] = fmaf(a1, b.z, acc1[2]);
                acc1[3] = fmaf(a1, b.w, acc1[3]);
            }
            __syncthreads();
        }
        float m0 = -3.4e38f, m1 = -3.4e38f;
        int a0i = 0, a1i = 0;
#pragma unroll
        for (int j = 0; j < 4; ++j) {
            int sg = col0 + tx * 4 + j;
            float mv = minv[sg];
            float s0 = acc0[j] * mv;
            float s1 = acc1[j] * mv;
            if (s0 > m0) { m0 = s0; a0i = sg; }
            if (s1 > m1) { m1 = s1; a1i = sg; }
        }
#pragma unroll
        for (int mk = 1; mk < 32; mk <<= 1) {
            float o0 = __shfl_xor(m0, mk, 32);
            int b0 = __shfl_xor(a0i, mk, 32);
            float o1 = __shfl_xor(m1, mk, 32);
            int b1 = __shfl_xor(a1i, mk, 32);
            if (o0 > m0 || (o0 == m0 && b0 < a0i)) { m0 = o0; a0i = b0; }
            if (o1 > m1 || (o1 == m1 && b1 < a1i)) { m1 = o1; a1i = b1; }
        }
        if (tx == 0) {
            int idx0 = g * XROWS + ty;
            int idx1 = g * XROWS + ty + 8;
            int tgt0 = idx0 < n ? idx0 : n - 1;
            int tgt1 = idx1 < n ? idx1 : n - 1;
            unsigned long long pk0 =
                ((unsigned long long)fenc(m0) << 32) | (unsigned)(2047 - a0i);
            unsigned long long pk1 =
                ((unsigned long long)fenc(m1) << 32) | (unsigned)(2047 - a1i);
            atomicMax(&packed[tgt0], pk0);
            atomicMax(&packed[tgt1], pk1);
        }
    }
}

__global__ __launch_bounds__(256) void unpack_k(const int* __restrict__ cnt,
                                                const int* __restrict__ list,
                                                const unsigned long long* __restrict__ packed,
                                                int* __restrict__ rowarg) {
    int p = blockIdx.x * 256 + threadIdx.x;
    if (p < *cnt) {
        int slot = 2047 - (int)(unsigned)(packed[p] & 0xFFFFFFFFull);
        rowarg[list[p]] = slot;
    }
}

// ---------------- refine: fp32 rowmax for ALL rows given final argmax ----------------

__global__ __launch_bounds__(256) void refine_k(const float* __restrict__ z,
                                                const float* __restrict__ mem,
                                                const float* __restrict__ zinv,
                                                const float* __restrict__ minv,
                                                const int* __restrict__ rowarg,
                                                float* __restrict__ rowmax) {
    int row = blockIdx.x * 4 + (threadIdx.x >> 6);
    int lane = threadIdx.x & 63;
    int a = rowarg[row];
    const float4* zp = reinterpret_cast<const float4*>(z + (size_t)row * H_DIM);
    const float4* mp = reinterpret_cast<const float4*>(mem + (size_t)a * H_DIM);
    float d = 0.f;
#pragma unroll
    for (int j = 0; j < 2; ++j) {
        float4 x = zp[lane + j * 64];
        float4 y = mp[lane + j * 64];
        d += x.x * y.x + x.y * y.y + x.z * y.z + x.w * y.w;
    }
#pragma unroll
    for (int m = 32; m >= 1; m >>= 1) d += __shfl_xor(d, m, 64);
    if (lane == 0) rowmax[row] = d * zinv[row] * minv[a];
}

// ---------------- per-slot update: gather members, masked softmax, renormalize ----------------

__global__ __launch_bounds__(256) void slot_update_k(const float* __restrict__ mem,
                                                     const float* __restrict__ z,
                                                     const float* __restrict__ rowmax,
                                                     const int* __restrict__ rowarg,
                                                     float* __restrict__ outmem) {
    __shared__ int members[MCAP];
    __shared__ float uval[MCAP];
    __shared__ int cnt;
    __shared__ float red[4];
    __shared__ float bcast;
    int slot = blockIdx.x, tid = threadIdx.x;
    if (tid == 0) cnt = 0;
    __syncthreads();
    for (int b = tid; b < B_ROWS; b += 256) {
        if (rowarg[b] == slot) {
            int p = atomicAdd(&cnt, 1);
            if (p < MCAP) members[p] = b;
        }
    }
    __syncthreads();
    int n = min(cnt, MCAP);
    size_t base = (size_t)slot * H_DIM;
    if (n == 0) {
        for (int h = tid; h < H_DIM; h += 256) outmem[base + h] = mem[base + h];
        return;
    }
    float lm = -3.4e38f;
    for (int j = tid; j < n; j += 256) lm = fmaxf(lm, rowmax[members[j]]);
#pragma unroll
    for (int m = 32; m >= 1; m >>= 1) lm = fmaxf(lm, __shfl_xor(lm, m, 64));
    if ((tid & 63) == 0) red[tid >> 6] = lm;
    __syncthreads();
    if (tid == 0) bcast = fmaxf(fmaxf(red[0], red[1]), fmaxf(red[2], red[3]));
    __syncthreads();
    float mslot = bcast;
    __syncthreads();
    float ls = 0.f;
    for (int j = tid; j < n; j += 256) {
        float u = expf(rowmax[members[j]] - mslot);
        uval[j] = u;
        ls += u;
    }
#pragma unroll
    for (int m = 32; m >= 1; m >>= 1) ls += __shfl_xor(ls, m, 64);
    if ((tid & 63) == 0) red[tid >> 6] = ls;
    __syncthreads();
    if (tid == 0) bcast = (red[0] + red[1]) + (red[2] + red[3]);
    __syncthreads();
    float dinv = 1.0f / fmaxf(bcast, 1e-30f);
    float v0 = mem[base + tid];
    float v1 = mem[base + 256 + tid];
    for (int j = 0; j < n; ++j) {
        float u = uval[j] * dinv;
        size_t zb = (size_t)members[j] * H_DIM;
        v0 = fmaf(u, z[zb + tid], v0);
        v1 = fmaf(u, z[zb + 256 + tid], v1);
    }
    float s = v0 * v0 + v1 * v1;
#pragma unroll
    for (int m = 32; m >= 1; m >>= 1) s += __shfl_xor(s, m, 64);
    if ((tid & 63) == 0) red[tid >> 6] = s;
    __syncthreads();
    if (tid == 0) bcast = (red[0] + red[1]) + (red[2] + red[3]);
    __syncthreads();
    float ninv = 1.0f / fmaxf(sqrtf(bcast), 1e-12f);
    outmem[base + tid] = v0 * ninv;
    outmem[base + 256 + tid] = v1 * ninv;
}

// ---------------- launch ----------------

extern "C" void kernel_launch(void* const* d_in, const int* in_sizes, int n_in,
                              void* d_out, int out_size, void* d_ws, size_t ws_size,
                              hipStream_t stream) {
    const float* z = (const float*)d_in[0];
    const float* mem = (const float*)d_in[1];
    float* out_zhat = (float*)d_out;
    float* out_mem = out_zhat + (size_t)B_ROWS * H_DIM;

    char* ws = (char*)d_ws;
    size_t off = 0;
    auto alloc = [&](size_t bytes) -> void* {
        void* p = ws + off;
        off += (bytes + 255) & ~(size_t)255;
        return p;
    };
    float* rowmax = (float*)alloc((size_t)B_ROWS * 4);
    int* rowarg = (int*)alloc((size_t)B_ROWS * 4);
    float* rowm2 = (float*)alloc((size_t)B_ROWS * 4);
    float* zinv = (float*)alloc((size_t)B_ROWS * 4);
    float* minv = (float*)alloc((size_t)N_SLOTS * 4);
    short* mn_sw = (short*)alloc((size_t)N_SLOTS * H_DIM * 2);
    short* memT_sw = (short*)alloc((size_t)H_DIM * N_SLOTS * 2);
    int* fcnt = (int*)alloc(256);
    int* flist = (int*)alloc((size_t)B_ROWS * 4);
    unsigned long long* packed = (unsigned long long*)alloc((size_t)B_ROWS * 8);

    prep_z_k<<<B_ROWS / 4, 256, 0, stream>>>(z, zinv, fcnt);
    prep_mem_k<<<N_SLOTS / 4, 256, 0, stream>>>(mem, minv, mn_sw);
    prep_memT_k<<<dim3(N_SLOTS / 64, H_DIM / 64), 256, 0, stream>>>(mem, memT_sw);
    zhat_k<<<B_ROWS / 64, 512, 0, stream>>>(z, mn_sw, memT_sw, zinv,
                                            rowmax, rowarg, rowm2, out_zhat);
    flag_k<<<B_ROWS / 256, 256, 0, stream>>>(rowmax, rowm2, fcnt, flist, packed);
    exact_k<<<2048, 256, 0, stream>>>(z, mem, minv, fcnt, flist, packed);
    unpack_k<<<B_ROWS / 256, 256, 0, stream>>>(fcnt, flist, packed, rowarg);
    refine_k<<<B_ROWS / 4, 256, 0, stream>>>(z, mem, zinv, minv, rowarg, rowmax);
    slot_update_k<<<N_SLOTS, 256, 0, stream>>>(mem, z, rowmax, rowarg, out_mem);
}

// Round 9
// 479.188 us; speedup vs baseline: 1.3143x; 1.1766x over previous
//
#include <hip/hip_runtime.h>
#include <math.h>

#define B_ROWS 32768
#define N_SLOTS 2048
#define H_DIM 512
#define MCAP 4096

typedef __attribute__((ext_vector_type(8))) _Float16 f16x8;
typedef __attribute__((ext_vector_type(4))) float f32x4;

#define ZPL 132   // Pl stride (shorts)
#define FIX_MARGIN 2.5e-4f   // fp16 sims: gap-error sigma ~5e-5 -> 4.6 sigma margin
#define XROWS 16

__device__ __forceinline__ unsigned short f2h(float f) {
    union { _Float16 h; unsigned short u; } cv;
    cv.h = (_Float16)f;          // v_cvt_f16_f32, RTN
    return cv.u;
}
__device__ __forceinline__ unsigned pk2h(float a, float b) {
    return (unsigned)f2h(a) | ((unsigned)f2h(b) << 16);
}
// monotonic float->uint encode: a > b  <=>  fenc(a) > fenc(b)
__device__ __forceinline__ unsigned fenc(float f) {
    unsigned b = __float_as_uint(f);
    return (b & 0x80000000u) ? ~b : (b | 0x80000000u);
}

// async global->LDS, 16B per lane, LDS dest = wave-uniform base + lane*16
#define STAGE16(g, l) __builtin_amdgcn_global_load_lds( \
    (const __attribute__((address_space(1))) unsigned int*)(g), \
    (__attribute__((address_space(3))) unsigned int*)(l), 16, 0, 0)

// counted waits + raw barrier (T4): keep prefetch in flight across barriers
#define VWAIT4() asm volatile("s_waitcnt vmcnt(4)" ::: "memory")
#define LWAIT0() asm volatile("s_waitcnt lgkmcnt(0)" ::: "memory")

// ---------------- prep: reciprocal norms (+ fp16 conversions) ----------------

__global__ __launch_bounds__(256) void prep_z_k(const float* __restrict__ z,
                                                float* __restrict__ zinv,
                                                int* __restrict__ fcnt) {
    if (blockIdx.x == 0 && threadIdx.x == 0) *fcnt = 0;
    int row = blockIdx.x * 4 + (threadIdx.x >> 6);
    int lane = threadIdx.x & 63;
    const float4* p = reinterpret_cast<const float4*>(z + (size_t)row * H_DIM);
    float4 a = p[lane * 2];
    float4 b = p[lane * 2 + 1];
    float s = a.x * a.x + a.y * a.y + a.z * a.z + a.w * a.w
            + b.x * b.x + b.y * b.y + b.z * b.z + b.w * b.w;
#pragma unroll
    for (int m = 32; m >= 1; m >>= 1) s += __shfl_xor(s, m, 64);
    if (lane == 0) zinv[row] = 1.0f / fmaxf(sqrtf(s), 1e-12f);
}

// minv + normalized fp16 rows, XOR-swizzled within each 128B window
__global__ __launch_bounds__(256) void prep_mem_k(const float* __restrict__ mem,
                                                  float* __restrict__ minv,
                                                  short* __restrict__ mn_sw) {
    int row = blockIdx.x * 4 + (threadIdx.x >> 6);
    int lane = threadIdx.x & 63;
    const float4* p = reinterpret_cast<const float4*>(mem + (size_t)row * H_DIM);
    float4 a = p[lane * 2];
    float4 b = p[lane * 2 + 1];
    float s = a.x * a.x + a.y * a.y + a.z * a.z + a.w * a.w
            + b.x * b.x + b.y * b.y + b.z * b.z + b.w * b.w;
#pragma unroll
    for (int m = 32; m >= 1; m >>= 1) s += __shfl_xor(s, m, 64);
    float inv = 1.0f / fmaxf(sqrtf(s), 1e-12f);
    if (lane == 0) minv[row] = inv;
    uint4 w;
    w.x = pk2h(a.x * inv, a.y * inv);
    w.y = pk2h(a.z * inv, a.w * inv);
    w.z = pk2h(b.x * inv, b.y * inv);
    w.w = pk2h(b.z * inv, b.w * inv);
    char* dst = (char*)mn_sw + ((size_t)row << 10) + ((unsigned)(lane * 16) ^ (unsigned)((row & 7) << 4));
    *reinterpret_cast<uint4*>(dst) = w;
}

// raw mem transposed to [H][N] fp16, XOR-swizzled within each 128B window
__global__ __launch_bounds__(256) void prep_memT_k(const float* __restrict__ mem,
                                                   short* __restrict__ memT_sw) {
    __shared__ short Ts[64][72];
    int bs = blockIdx.x;          // slot tile (32)
    int bh = blockIdx.y;          // h tile (8)
    int tid = threadIdx.x;
    {
        int s = tid >> 2, c4 = (tid & 3) * 16;
        const float* src = mem + (size_t)(bs * 64 + s) * H_DIM + bh * 64 + c4;
#pragma unroll
        for (int j = 0; j < 4; ++j) {
            float4 v = *reinterpret_cast<const float4*>(src + j * 4);
            Ts[s][c4 + j * 4 + 0] = (short)f2h(v.x);
            Ts[s][c4 + j * 4 + 1] = (short)f2h(v.y);
            Ts[s][c4 + j * 4 + 2] = (short)f2h(v.z);
            Ts[s][c4 + j * 4 + 3] = (short)f2h(v.w);
        }
    }
    __syncthreads();
    int h = tid >> 2, q = tid & 3;
    unsigned w[8];
#pragma unroll
    for (int k = 0; k < 8; ++k) {
        unsigned lo = (unsigned short)Ts[q * 16 + 2 * k][h];
        unsigned hi = (unsigned short)Ts[q * 16 + 2 * k + 1][h];
        w[k] = lo | (hi << 16);
    }
    uint4 c0 = {w[0], w[1], w[2], w[3]};
    uint4 c1 = {w[4], w[5], w[6], w[7]};
    char* dst = (char*)memT_sw + (size_t)(bh * 64 + h) * (N_SLOTS * 2);
    unsigned sw = (unsigned)((h & 7) << 4);
    unsigned b0 = (unsigned)(bs * 128 + q * 32);
    *reinterpret_cast<uint4*>(dst + (b0 ^ sw)) = c0;
    *reinterpret_cast<uint4*>(dst + ((b0 + 16) ^ sw)) = c1;
}

// ---------------- fused zhat: counted-vmcnt 4-buffer pipeline, PV 2x V-reuse (R6 proven) ----------------

__global__ __launch_bounds__(512, 2) void zhat_k(const float* __restrict__ z,
                                                 const short* __restrict__ mn_sw,
                                                 const short* __restrict__ memT_sw,
                                                 const float* __restrict__ zinv,
                                                 float* __restrict__ rowmax,
                                                 int* __restrict__ rowarg,
                                                 float* __restrict__ rowm2,
                                                 float* __restrict__ out) {
    __shared__ __align__(16) short Mb[4][8192];      // 4 x 16KB rotation (M [128][64] / V [64][128])
    __shared__ __align__(16) short Pl[64 * ZPL];     // P [64 rows][128 slots] padded
    __shared__ float pm1[2][64], pm2[2][64], ps[2][64];
    __shared__ int pa1[2][64], pa2[2][64];

    int tid = threadIdx.x;
    int row0 = blockIdx.x * 64;
    int wave = tid >> 6, lane = tid & 63;
    int lm = lane & 15, quad = lane >> 4;
    int rt = wave & 3;          // QK wave mapping: 16 rows x 64 slots
    int wg = wave >> 2;
    int rh = wave & 1;          // PV wave mapping: 32 rows (pair of row-tiles) x 16 h per chunk
    int wc = wave >> 1;         // h-tile within 64-h chunk
    const int swz = (lm & 7) << 4;

    // M-tile stage: 128 rows x 128B (pre-swizzled rows copied linearly); 2 loads/wave
#define STAGE_M(buf, c0, kc) do { \
        const char* _g = (const char*)mn_sw + ((size_t)((c0) + wave * 16 + (lane >> 3)) << 10) \
                         + ((kc) << 7) + ((lane & 7) << 4); \
        short* _l = &Mb[buf][wave * 16 * 64]; \
        STAGE16(_g, _l); \
        STAGE16(_g + (8 << 10), _l + 8 * 64); \
    } while (0)

    // V-tile stage: 64 h-rows x 256B segment of memT; 2 loads/wave
#define STAGE_V(buf, c0, hc) do { \
        const char* _g = (const char*)memT_sw + ((size_t)((hc) * 64 + wave * 8 + (lane >> 4)) << 12) \
                         + ((size_t)(c0) << 1) + ((lane & 15) << 4); \
        short* _l = &Mb[buf][wave * 8 * 128]; \
        STAGE16(_g, _l); \
        STAGE16(_g + (4 << 12), _l + 4 * 128); \
    } while (0)

    // prologue: stage first two M-tiles (depth-2 pipeline)
    STAGE_M(0, 0, 0);
    STAGE_M(1, 0, 1);

    int zrow = row0 + rt * 16 + lm;
    float zi = zinv[zrow];
    f16x8 Zfr[16];
#pragma unroll
    for (int kt = 0; kt < 16; ++kt) {
        const float* zp = z + (size_t)zrow * H_DIM + kt * 32 + quad * 8;
        float4 a = *reinterpret_cast<const float4*>(zp);
        float4 b = *reinterpret_cast<const float4*>(zp + 4);
        union { uint4 u; f16x8 v; } cv;
        cv.u.x = pk2h(a.x * zi, a.y * zi);
        cv.u.y = pk2h(a.z * zi, a.w * zi);
        cv.u.z = pk2h(b.x * zi, b.y * zi);
        cv.u.w = pk2h(b.z * zi, b.w * zi);
        Zfr[kt] = cv.v;
    }

    f32x4 acc[16];
#pragma unroll
    for (int t = 0; t < 16; ++t) acc[t] = (f32x4){0.f, 0.f, 0.f, 0.f};
    float rm1[4], rm2[4], lsum[4];
    int ra1[4], ra2[4];
#pragma unroll
    for (int r = 0; r < 4; ++r) {
        rm1[r] = -3.4e38f; rm2[r] = -3.4e38f; lsum[r] = 0.f; ra1[r] = 0; ra2[r] = 0;
    }

    for (int ct = 0; ct < 16; ++ct) {
        int col0 = ct * 128;
        int col0n = (ct < 15) ? col0 + 128 : 0;   // ct=15: dummy re-stage (never read)
        f32x4 sacc[4];
#pragma unroll
        for (int i = 0; i < 4; ++i) sacc[i] = (f32x4){0.f, 0.f, 0.f, 0.f};

        // ---- QK: 8 K-steps; stage(t+2) || compute(t); counted vmcnt ----
#pragma unroll
        for (int kc = 0; kc < 8; ++kc) {
            if (kc < 6)       STAGE_M((kc + 2) & 3, col0, kc + 2);
            else if (kc == 6) STAGE_V(0, col0, 0);
            else              STAGE_V(1, col0, 1);
            VWAIT4();                    // tile kc landed; kc+1/kc+2 stay in flight
            __builtin_amdgcn_s_barrier();
            __builtin_amdgcn_s_setprio(1);
#pragma unroll
            for (int ks = 0; ks < 2; ++ks) {
                f16x8 af = Zfr[kc * 2 + ks];
#pragma unroll
                for (int i = 0; i < 4; ++i) {
                    int srow = (wg * 4 + i) * 16 + lm;
                    int kb = (ks * 64 + quad * 16) ^ swz;
                    f16x8 bfr = *reinterpret_cast<const f16x8*>(
                        (const char*)&Mb[kc & 3][0] + srow * 128 + kb);
                    sacc[i] = __builtin_amdgcn_mfma_f32_16x16x32_f16(af, bfr, sacc[i], 0, 0, 0);
                }
            }
            __builtin_amdgcn_s_setprio(0);
        }

        // ---- softmax (|sim|<=1: no max subtraction) + running top-2 + P write ----
#pragma unroll
        for (int i = 0; i < 4; ++i) {
            int sl = (wg * 4 + i) * 16 + lm;
            int sg = col0 + sl;
#pragma unroll
            for (int r = 0; r < 4; ++r) {
                float v = sacc[i][r];
                if (v > rm1[r]) { rm2[r] = rm1[r]; ra2[r] = ra1[r]; rm1[r] = v; ra1[r] = sg; }
                else if (v > rm2[r]) { rm2[r] = v; ra2[r] = sg; }
                float p = __expf(v);
                lsum[r] += p;
                Pl[(rt * 16 + quad * 4 + r) * ZPL + sl] = (short)f2h(p);
            }
        }
        LWAIT0();                        // Pl writes visible; V0/V1 stages stay in flight
        __builtin_amdgcn_s_barrier();

        // hoisted PV A-fragments for BOTH owned row-tiles (read once per ct)
        f16x8 pa_all[2][4];
#pragma unroll
        for (int rtl = 0; rtl < 2; ++rtl)
#pragma unroll
            for (int ks = 0; ks < 4; ++ks)
                pa_all[rtl][ks] = *reinterpret_cast<const f16x8*>(
                    &Pl[((rh * 2 + rtl) * 16 + lm) * ZPL + ks * 32 + quad * 8]);

        // ---- PV: 8 h-steps; stage(t+2) || compute(t); each V-frag feeds 2 row-tiles ----
#pragma unroll
        for (int hc = 0; hc < 8; ++hc) {
            if (hc < 6)       STAGE_V((hc + 2) & 3, col0, hc + 2);
            else if (hc == 6) STAGE_M(0, col0n, 0);
            else              STAGE_M(1, col0n, 1);
            VWAIT4();
            __builtin_amdgcn_s_barrier();
            __builtin_amdgcn_s_setprio(1);
#pragma unroll
            for (int ks = 0; ks < 4; ++ks) {
                int hl = wc * 16 + lm;
                int kb = (ks * 64 + quad * 16) ^ swz;
                f16x8 vf = *reinterpret_cast<const f16x8*>(
                    (const char*)&Mb[hc & 3][0] + hl * 256 + kb);
                acc[hc * 2 + 0] = __builtin_amdgcn_mfma_f32_16x16x32_f16(pa_all[0][ks], vf, acc[hc * 2 + 0], 0, 0, 0);
                acc[hc * 2 + 1] = __builtin_amdgcn_mfma_f32_16x16x32_f16(pa_all[1][ks], vf, acc[hc * 2 + 1], 0, 0, 0);
            }
            __builtin_amdgcn_s_setprio(0);
        }
    }
    __syncthreads();   // full drain (dummy stages) before epilogue LDS reuse

    // ---- final merges: 16-lane butterfly (disjoint slot subsets), then wg merge ----
#pragma unroll
    for (int mk = 1; mk < 16; mk <<= 1) {
#pragma unroll
        for (int r = 0; r < 4; ++r) {
            float n1 = __shfl_xor(rm1[r], mk, 16);
            int b1 = __shfl_xor(ra1[r], mk, 16);
            float n2 = __shfl_xor(rm2[r], mk, 16);
            int b2 = __shfl_xor(ra2[r], mk, 16);
            if (n1 > rm1[r]) {
                bool c = rm1[r] > n2;
                rm2[r] = c ? rm1[r] : n2; ra2[r] = c ? ra1[r] : b2;
                rm1[r] = n1; ra1[r] = b1;
            } else {
                bool c = n1 > rm2[r];
                rm2[r] = c ? n1 : rm2[r]; ra2[r] = c ? b1 : ra2[r];
            }
            lsum[r] += __shfl_xor(lsum[r], mk, 16);
        }
    }
    if (lm == 0) {
#pragma unroll
        for (int r = 0; r < 4; ++r) {
            int rl = rt * 16 + quad * 4 + r;
            pm1[wg][rl] = rm1[r]; pa1[wg][rl] = ra1[r];
            pm2[wg][rl] = rm2[r]; pa2[wg][rl] = ra2[r];
            ps[wg][rl] = lsum[r];
        }
    }
    __syncthreads();
    if (wave == 0) {
        int r = lane;
        float gm1 = pm1[0][r], gm2 = pm2[0][r];
        int ga1 = pa1[0][r], ga2 = pa2[0][r];
        float n1 = pm1[1][r]; int b1 = pa1[1][r];
        float n2 = pm2[1][r]; int b2 = pa2[1][r];
        if (n1 > gm1) {
            bool c = gm1 > n2;
            gm2 = c ? gm1 : n2; ga2 = c ? ga1 : b2;
            gm1 = n1; ga1 = b1;
        } else {
            bool c = n1 > gm2;
            gm2 = c ? n1 : gm2; ga2 = c ? b1 : ga2;
        }
        rowmax[row0 + r] = gm1; rowarg[row0 + r] = ga1; rowm2[row0 + r] = gm2;
    }
    float linv2[2][4];
#pragma unroll
    for (int rtl = 0; rtl < 2; ++rtl)
#pragma unroll
        for (int r = 0; r < 4; ++r) {
            int rl = (rh * 2 + rtl) * 16 + quad * 4 + r;
            linv2[rtl][r] = 1.0f / (ps[0][rl] + ps[1][rl]);
        }
#pragma unroll
    for (int hc = 0; hc < 8; ++hc)
#pragma unroll
        for (int rtl = 0; rtl < 2; ++rtl) {
            int t = hc * 2 + rtl;
            int h = hc * 64 + wc * 16 + lm;
#pragma unroll
            for (int r = 0; r < 4; ++r) {
                int rg = row0 + (rh * 2 + rtl) * 16 + quad * 4 + r;
                out[(size_t)rg * H_DIM + h] = acc[t][r] * linv2[rtl][r];
            }
        }
}

// ---------------- flag near-tie rows into a compact worklist ----------------

__global__ __launch_bounds__(256) void flag_k(const float* __restrict__ rowmax,
                                              const float* __restrict__ rowm2,
                                              int* __restrict__ cnt,
                                              int* __restrict__ list,
                                              unsigned long long* __restrict__ packed) {
    int b = blockIdx.x * 256 + threadIdx.x;
    if (rowmax[b] - rowm2[b] < FIX_MARGIN) {
        int p = atomicAdd(cnt, 1);
        list[p] = b;
        packed[p] = 0ull;
    }
}

// ---------------- exact: full fp32 argmax over all slots for flagged rows (R6 proven) ----------------

__global__ __launch_bounds__(256) void exact_k(const float* __restrict__ z,
                                               const float* __restrict__ mem,
                                               const float* __restrict__ minv,
                                               const int* __restrict__ cnt,
                                               const int* __restrict__ list,
                                               unsigned long long* __restrict__ packed) {
    __shared__ float As[32][XROWS + 4];
    __shared__ float Bs[32][132];
    __shared__ int rows[XROWS];
    int tid = threadIdx.x;
    int tx = tid & 15, ty = tid >> 4;
    int n = *cnt;
    int ngroups = (n + XROWS - 1) / XROWS;
    int nunits = ngroups * 16;

    for (int u = blockIdx.x; u < nunits; u += gridDim.x) {
        int g = u >> 4;
        int col0 = (u & 15) * 128;
        __syncthreads();   // protect rows[] reuse across units
        if (tid < XROWS) {
            int idx = g * XROWS + tid;
            rows[tid] = list[idx < n ? idx : n - 1];
        }
        __syncthreads();
        float acc[8];
#pragma unroll
        for (int j = 0; j < 8; ++j) acc[j] = 0.f;
        for (int kc = 0; kc < H_DIM; kc += 32) {
            if (tid < 128) {
                int r = tid >> 3, k4 = (tid & 7) * 4;
                float4 v = *reinterpret_cast<const float4*>(z + (size_t)rows[r] * H_DIM + kc + k4);
                As[k4 + 0][r] = v.x;
                As[k4 + 1][r] = v.y;
                As[k4 + 2][r] = v.z;
                As[k4 + 3][r] = v.w;
            }
            int sl = tid >> 1, kq = (tid & 1) * 16;
#pragma unroll
            for (int j = 0; j < 4; ++j) {
                float4 v = *reinterpret_cast<const float4*>(mem + (size_t)(col0 + sl) * H_DIM + kc + kq + j * 4);
                Bs[kq + j * 4 + 0][sl] = v.x;
                Bs[kq + j * 4 + 1][sl] = v.y;
                Bs[kq + j * 4 + 2][sl] = v.z;
                Bs[kq + j * 4 + 3][sl] = v.w;
            }
            __syncthreads();
#pragma unroll 4
            for (int k = 0; k < 32; ++k) {
                float av = As[k][ty];
                const float4 b0 = *reinterpret_cast<const float4*>(&Bs[k][tx * 8]);
                const float4 b1 = *reinterpret_cast<const float4*>(&Bs[k][tx * 8 + 4]);
                acc[0] = fmaf(av, b0.x, acc[0]);
                acc[1] = fmaf(av, b0.y, acc[1]);
                acc[2] = fmaf(av, b0.z, acc[2]);
                acc[3] = fmaf(av, b0.w, acc[3]);
                acc[4] = fmaf(av, b1.x, acc[4]);
                acc[5] = fmaf(av, b1.y, acc[5]);
                acc[6] = fmaf(av, b1.z, acc[6]);
                acc[7] = fmaf(av, b1.w, acc[7]);
            }
            __syncthreads();
        }
        float runM = -3.4e38f;
        int runA = 0;
#pragma unroll
        for (int j = 0; j < 8; ++j) {
            int sg = col0 + tx * 8 + j;
            float s = acc[j] * minv[sg];
            if (s > runM) { runM = s; runA = sg; }
        }
#pragma unroll
        for (int mk = 1; mk < 16; mk <<= 1) {
            float om = __shfl_xor(runM, mk, 16);
            int oa = __shfl_xor(runA, mk, 16);
            if (om > runM || (om == runM && oa < runA)) { runM = om; runA = oa; }
        }
        if (tx == 0) {
            int idx = g * XROWS + ty;
            int tgt = idx < n ? idx : n - 1;
            unsigned long long pk =
                ((unsigned long long)fenc(runM) << 32) | (unsigned)(2047 - runA);
            atomicMax(&packed[tgt], pk);
        }
    }
}

__global__ __launch_bounds__(256) void unpack_k(const int* __restrict__ cnt,
                                                const int* __restrict__ list,
                                                const unsigned long long* __restrict__ packed,
                                                int* __restrict__ rowarg) {
    int p = blockIdx.x * 256 + threadIdx.x;
    if (p < *cnt) {
        int slot = 2047 - (int)(unsigned)(packed[p] & 0xFFFFFFFFull);
        rowarg[list[p]] = slot;
    }
}

// ---------------- counting-sort of rows by slot (replaces slot_update's full scan) ----------------

__global__ void zero_counts_k(int* __restrict__ counts) {
    counts[blockIdx.x * 256 + threadIdx.x] = 0;
}

__global__ __launch_bounds__(256) void hist_k(const int* __restrict__ rowarg,
                                              int* __restrict__ counts) {
    int b = blockIdx.x * 256 + threadIdx.x;
    atomicAdd(&counts[rowarg[b]], 1);
}

__global__ __launch_bounds__(256) void scan_k(const int* __restrict__ counts,
                                              int* __restrict__ offs,
                                              int* __restrict__ cursor) {
    __shared__ int s[N_SLOTS];
    int tid = threadIdx.x;
    for (int i = tid; i < N_SLOTS; i += 256) s[i] = counts[i];
    __syncthreads();
    for (int d = 1; d < N_SLOTS; d <<= 1) {
        int v[8];
#pragma unroll
        for (int k = 0; k < 8; ++k) {
            int i = tid + k * 256;
            v[k] = (i >= d) ? s[i - d] : 0;
        }
        __syncthreads();
#pragma unroll
        for (int k = 0; k < 8; ++k) s[tid + k * 256] += v[k];
        __syncthreads();
    }
    for (int i = tid; i < N_SLOTS; i += 256) {
        int e = (i == 0) ? 0 : s[i - 1];
        offs[i] = e;
        cursor[i] = e;
    }
    if (tid == 0) offs[N_SLOTS] = s[N_SLOTS - 1];
}

__global__ __launch_bounds__(256) void scatter_k(const int* __restrict__ rowarg,
                                                 int* __restrict__ cursor,
                                                 int* __restrict__ mlist) {
    int b = blockIdx.x * 256 + threadIdx.x;
    int p = atomicAdd(&cursor[rowarg[b]], 1);
    mlist[p] = b;
}

// ---------------- refine: fp32 rowmax for ALL rows given final argmax ----------------

__global__ __launch_bounds__(256) void refine_k(const float* __restrict__ z,
                                                const float* __restrict__ mem,
                                                const float* __restrict__ zinv,
                                                const float* __restrict__ minv,
                                                const int* __restrict__ rowarg,
                                                float* __restrict__ rowmax) {
    int row = blockIdx.x * 4 + (threadIdx.x >> 6);
    int lane = threadIdx.x & 63;
    int a = rowarg[row];
    const float4* zp = reinterpret_cast<const float4*>(z + (size_t)row * H_DIM);
    const float4* mp = reinterpret_cast<const float4*>(mem + (size_t)a * H_DIM);
    float d = 0.f;
#pragma unroll
    for (int j = 0; j < 2; ++j) {
        float4 x = zp[lane + j * 64];
        float4 y = mp[lane + j * 64];
        d += x.x * y.x + x.y * y.y + x.z * y.z + x.w * y.w;
    }
#pragma unroll
    for (int m = 32; m >= 1; m >>= 1) d += __shfl_xor(d, m, 64);
    if (lane == 0) rowmax[row] = d * zinv[row] * minv[a];
}

// ---------------- per-slot update: compact member list, masked softmax, renormalize ----------------

__global__ __launch_bounds__(256) void slot_update_k(const float* __restrict__ mem,
                                                     const float* __restrict__ z,
                                                     const float* __restrict__ rowmax,
                                                     const int* __restrict__ offs,
                                                     const int* __restrict__ mlist,
                                                     float* __restrict__ outmem) {
    __shared__ int memb[MCAP];
    __shared__ float uval[MCAP];
    __shared__ float red[4];
    __shared__ float bcast;
    int slot = blockIdx.x, tid = threadIdx.x;
    int off = offs[slot];
    int n = min(offs[slot + 1] - off, MCAP);
    size_t base = (size_t)slot * H_DIM;
    if (n == 0) {
        for (int h = tid; h < H_DIM; h += 256) outmem[base + h] = mem[base + h];
        return;
    }
    float lm = -3.4e38f;
    for (int j = tid; j < n; j += 256) {
        int m = mlist[off + j];
        memb[j] = m;
        float rm = rowmax[m];
        uval[j] = rm;
        lm = fmaxf(lm, rm);
    }
#pragma unroll
    for (int m = 32; m >= 1; m >>= 1) lm = fmaxf(lm, __shfl_xor(lm, m, 64));
    if ((tid & 63) == 0) red[tid >> 6] = lm;
    __syncthreads();
    if (tid == 0) bcast = fmaxf(fmaxf(red[0], red[1]), fmaxf(red[2], red[3]));
    __syncthreads();
    float mslot = bcast;
    __syncthreads();
    float ls = 0.f;
    for (int j = tid; j < n; j += 256) {
        float u = expf(uval[j] - mslot);
        uval[j] = u;
        ls += u;
    }
#pragma unroll
    for (int m = 32; m >= 1; m >>= 1) ls += __shfl_xor(ls, m, 64);
    if ((tid & 63) == 0) red[tid >> 6] = ls;
    __syncthreads();
    if (tid == 0) bcast = (red[0] + red[1]) + (red[2] + red[3]);
    __syncthreads();
    float dinv = 1.0f / fmaxf(bcast, 1e-30f);
    float v0 = mem[base + tid];
    float v1 = mem[base + 256 + tid];
    for (int j = 0; j < n; ++j) {
        float u = uval[j] * dinv;
        size_t zb = (size_t)memb[j] * H_DIM;
        v0 = fmaf(u, z[zb + tid], v0);
        v1 = fmaf(u, z[zb + 256 + tid], v1);
    }
    float s = v0 * v0 + v1 * v1;
#pragma unroll
    for (int m = 32; m >= 1; m >>= 1) s += __shfl_xor(s, m, 64);
    if ((tid & 63) == 0) red[tid >> 6] = s;
    __syncthreads();
    if (tid == 0) bcast = (red[0] + red[1]) + (red[2] + red[3]);
    __syncthreads();
    float ninv = 1.0f / fmaxf(sqrtf(bcast), 1e-12f);
    outmem[base + tid] = v0 * ninv;
    outmem[base + 256 + tid] = v1 * ninv;
}

// ---------------- launch ----------------

extern "C" void kernel_launch(void* const* d_in, const int* in_sizes, int n_in,
                              void* d_out, int out_size, void* d_ws, size_t ws_size,
                              hipStream_t stream) {
    const float* z = (const float*)d_in[0];
    const float* mem = (const float*)d_in[1];
    float* out_zhat = (float*)d_out;
    float* out_mem = out_zhat + (size_t)B_ROWS * H_DIM;

    char* ws = (char*)d_ws;
    size_t off = 0;
    auto alloc = [&](size_t bytes) -> void* {
        void* p = ws + off;
        off += (bytes + 255) & ~(size_t)255;
        return p;
    };
    float* rowmax = (float*)alloc((size_t)B_ROWS * 4);
    int* rowarg = (int*)alloc((size_t)B_ROWS * 4);
    float* rowm2 = (float*)alloc((size_t)B_ROWS * 4);
    float* zinv = (float*)alloc((size_t)B_ROWS * 4);
    float* minv = (float*)alloc((size_t)N_SLOTS * 4);
    short* mn_sw = (short*)alloc((size_t)N_SLOTS * H_DIM * 2);
    short* memT_sw = (short*)alloc((size_t)H_DIM * N_SLOTS * 2);
    int* fcnt = (int*)alloc(256);
    int* flist = (int*)alloc((size_t)B_ROWS * 4);
    unsigned long long* packed = (unsigned long long*)alloc((size_t)B_ROWS * 8);
    int* counts = (int*)alloc((size_t)N_SLOTS * 4);
    int* offs = (int*)alloc((size_t)(N_SLOTS + 1) * 4);
    int* cursor = (int*)alloc((size_t)N_SLOTS * 4);
    int* mlist = (int*)alloc((size_t)B_ROWS * 4);

    prep_z_k<<<B_ROWS / 4, 256, 0, stream>>>(z, zinv, fcnt);
    prep_mem_k<<<N_SLOTS / 4, 256, 0, stream>>>(mem, minv, mn_sw);
    prep_memT_k<<<dim3(N_SLOTS / 64, H_DIM / 64), 256, 0, stream>>>(mem, memT_sw);
    zero_counts_k<<<N_SLOTS / 256, 256, 0, stream>>>(counts);
    zhat_k<<<B_ROWS / 64, 512, 0, stream>>>(z, mn_sw, memT_sw, zinv,
                                            rowmax, rowarg, rowm2, out_zhat);
    flag_k<<<B_ROWS / 256, 256, 0, stream>>>(rowmax, rowm2, fcnt, flist, packed);
    exact_k<<<2048, 256, 0, stream>>>(z, mem, minv, fcnt, flist, packed);
    unpack_k<<<B_ROWS / 256, 256, 0, stream>>>(fcnt, flist, packed, rowarg);
    hist_k<<<B_ROWS / 256, 256, 0, stream>>>(rowarg, counts);
    scan_k<<<1, 256, 0, stream>>>(counts, offs, cursor);
    scatter_k<<<B_ROWS / 256, 256, 0, stream>>>(rowarg, cursor, mlist);
    refine_k<<<B_ROWS / 4, 256, 0, stream>>>(z, mem, zinv, minv, rowarg, rowmax);
    slot_update_k<<<N_SLOTS, 256, 0, stream>>>(mem, z, rowmax, offs, mlist, out_mem);
}